// Round 1
// baseline (754.881 us; speedup 1.0000x reference)
//
#include <hip/hip_runtime.h>
#include <hip/hip_bf16.h>

#define NN 50000
#define NE 800000
#define CI 64
#define CO 128

typedef __attribute__((ext_vector_type(8))) short bf16x8;
typedef __attribute__((ext_vector_type(4))) float f32x4;

__device__ __forceinline__ unsigned short f2bf(float f) {
  unsigned int u = __float_as_uint(f);
  u += 0x7fffu + ((u >> 16) & 1u);   // RNE; inputs are finite
  return (unsigned short)(u >> 16);
}
__device__ __forceinline__ float bf2f_lo(unsigned int p) { return __uint_as_float(p << 16); }
__device__ __forceinline__ float bf2f_hi(unsigned int p) { return __uint_as_float(p & 0xffff0000u); }

// ---------------- CSR build ----------------
__global__ void k_count(const int* __restrict__ dst, int* __restrict__ deg) {
  int e = blockIdx.x * blockDim.x + threadIdx.x;
  if (e < NE) atomicAdd(&deg[dst[e]], 1);
}

__global__ __launch_bounds__(1024) void k_scan(const int* __restrict__ deg, int* __restrict__ row_off) {
  __shared__ int s[1024];
  __shared__ int s_base;
  if (threadIdx.x == 0) s_base = 0;
  __syncthreads();
  for (int base = 0; base < NN; base += 1024) {
    int i = base + (int)threadIdx.x;
    int v = (i < NN) ? deg[i] : 0;
    s[threadIdx.x] = v;
    __syncthreads();
    for (int off = 1; off < 1024; off <<= 1) {
      int t = (threadIdx.x >= (unsigned)off) ? s[threadIdx.x - off] : 0;
      __syncthreads();
      s[threadIdx.x] += t;
      __syncthreads();
    }
    if (i < NN) row_off[i] = s_base + s[threadIdx.x] - v;
    int tot = s[1023];
    __syncthreads();
    if (threadIdx.x == 0) s_base += tot;
    __syncthreads();
  }
  if (threadIdx.x == 0) row_off[NN] = s_base;
}

__global__ void k_fill(const int* __restrict__ src, const int* __restrict__ dst,
                       const int* __restrict__ row_off, int* __restrict__ cursor,
                       int* __restrict__ ssrc) {
  int e = blockIdx.x * blockDim.x + threadIdx.x;
  if (e < NE) {
    int d = dst[e];
    int pos = atomicAdd(&cursor[d], 1);
    ssrc[row_off[d] + pos] = src[e];
  }
}

// ---------------- bf16 conversions ----------------
__global__ void k_cvt_w(const float* __restrict__ w1, const float* __restrict__ m1,
                        const float* __restrict__ m2, const float* __restrict__ m3,
                        unsigned short* __restrict__ o) {
  int i = blockIdx.x * blockDim.x + threadIdx.x;
  if (i >= 57344) return;
  float v;
  if (i < 8192) v = w1[i];
  else if (i < 24576) v = m1[i - 8192];
  else if (i < 40960) v = m2[i - 24576];
  else v = m3[i - 40960];
  o[i] = f2bf(v);
}

__global__ void k_cvt_x(const float* __restrict__ x, unsigned short* __restrict__ xb) {
  int i = blockIdx.x * blockDim.x + threadIdx.x;
  if (i < NN * CI) xb[i] = f2bf(x[i]);
}

// ---------------- CSR gather (segment_sum) ----------------
// one 64-thread block per node; each lane owns 2 channels (bf16x2 / float2 loads)
__global__ __launch_bounds__(64) void k_gather(const int* __restrict__ row_off,
    const int* __restrict__ ssrc, const float* __restrict__ u32,
    const unsigned short* __restrict__ ubf, int first,
    unsigned short* __restrict__ agg) {
  int n = blockIdx.x;
  int t = threadIdx.x;
  int beg = row_off[n], end = row_off[n + 1];
  __shared__ int s_src[64];
  float a0 = 0.f, a1 = 0.f;
  for (int base = beg; base < end; base += 64) {
    int cnt = min(64, end - base);
    if (t < cnt) s_src[t] = ssrc[base + t];
    __syncthreads();
    if (first) {
      for (int j = 0; j < cnt; ++j) {
        float2 v = *(const float2*)(u32 + (size_t)s_src[j] * CO + t * 2);
        a0 += v.x; a1 += v.y;
      }
    } else {
      for (int j = 0; j < cnt; ++j) {
        unsigned int p = *(const unsigned int*)(ubf + (size_t)s_src[j] * CO + t * 2);
        a0 += bf2f_lo(p); a1 += bf2f_hi(p);
      }
    }
    __syncthreads();
  }
  unsigned int packed = ((unsigned int)f2bf(a1) << 16) | (unsigned int)f2bf(a0);
  *(unsigned int*)(agg + (size_t)n * CO + t * 2) = packed;
}

// ---------------- MFMA GEMM: C[n,o] = act(sum_k A[n,k]*W[o,k] + bias[o]) ----------------
// MODE 0: relu -> bf16 out. MODE 1: tanh, +xw, relu -> bf16 out. MODE 2: plain -> f32 out.
// block = 4 waves, each wave: 16 nodes x 128 outs (8 MFMA tiles), K in steps of 32.
template<int K, int MODE>
__global__ __launch_bounds__(256) void k_gemm(const unsigned short* __restrict__ A,
    const unsigned short* __restrict__ W, const float* __restrict__ bias,
    unsigned short* __restrict__ outb, float* __restrict__ outf,
    const float* __restrict__ xw) {
  int wave = threadIdx.x >> 6, lane = threadIdx.x & 63;
  int m = lane & 15, q = lane >> 4;
  int row0 = blockIdx.x * 64 + wave * 16;
  int arow = row0 + m; if (arow >= NN) arow = NN - 1;   // clamped loads; stores guarded
  const unsigned short* Ar = A + (size_t)arow * K;
  f32x4 acc[8];
#pragma unroll
  for (int tt = 0; tt < 8; ++tt) acc[tt] = (f32x4){0.f, 0.f, 0.f, 0.f};
#pragma unroll
  for (int ks = 0; ks < K; ks += 32) {
    bf16x8 a = *(const bf16x8*)(Ar + ks + q * 8);
#pragma unroll
    for (int tt = 0; tt < 8; ++tt) {
      bf16x8 b = *(const bf16x8*)(W + (size_t)(tt * 16 + m) * K + ks + q * 8);
      acc[tt] = __builtin_amdgcn_mfma_f32_16x16x32_bf16(a, b, acc[tt], 0, 0, 0);
    }
  }
#pragma unroll
  for (int tt = 0; tt < 8; ++tt) {
    int o = tt * 16 + m;
    float bv = bias[o];
#pragma unroll
    for (int r = 0; r < 4; ++r) {
      int node = row0 + q * 4 + r;
      if (node >= NN) continue;
      float v = acc[tt][r] + bv;
      if (MODE == 0) {
        v = fmaxf(v, 0.f);
        outb[(size_t)node * CO + o] = f2bf(v);
      } else if (MODE == 1) {
        float e = __expf(2.f * v);
        v = 1.f - 2.f / (e + 1.f);            // tanh
        v = fmaxf(xw[(size_t)node * CO + o] + v, 0.f);
        outb[(size_t)node * CO + o] = f2bf(v);
      } else {
        outf[(size_t)node * CO + o] = v;
      }
    }
  }
}

// ---------------- final readout ----------------
__global__ __launch_bounds__(256) void k_reduce(const unsigned short* __restrict__ u,
                                                float* __restrict__ g) {
  int ch2 = threadIdx.x & 63;    // channel-pair id
  int sub = threadIdx.x >> 6;    // 0..3 node stripes
  float a0 = 0.f, a1 = 0.f;
  for (int n = blockIdx.x * 4 + sub; n < NN; n += gridDim.x * 4) {
    unsigned int p = *(const unsigned int*)(u + (size_t)n * CO + ch2 * 2);
    a0 += bf2f_lo(p); a1 += bf2f_hi(p);
  }
  __shared__ float s0[256], s1[256];
  s0[threadIdx.x] = a0; s1[threadIdx.x] = a1;
  __syncthreads();
  if (sub == 0) {
    a0 = s0[ch2] + s0[64 + ch2] + s0[128 + ch2] + s0[192 + ch2];
    a1 = s1[ch2] + s1[64 + ch2] + s1[128 + ch2] + s1[192 + ch2];
    atomicAdd(&g[ch2 * 2], a0);
    atomicAdd(&g[ch2 * 2 + 1], a1);
  }
}

__global__ void k_final(const float* __restrict__ g, const float* __restrict__ w2,
                        const float* __restrict__ b2, float* __restrict__ outp) {
  __shared__ float sg[128];
  if (threadIdx.x < 128) sg[threadIdx.x] = g[threadIdx.x];
  __syncthreads();
  int j = threadIdx.x;
  if (j < 128) {
    float acc = b2[j];
    for (int c = 0; c < 128; ++c) acc += sg[c] * w2[j * 128 + c];
    outp[j] = acc;
  }
}

extern "C" void kernel_launch(void* const* d_in, const int* in_sizes, int n_in,
                              void* d_out, int out_size, void* d_ws, size_t ws_size,
                              hipStream_t stream) {
  (void)in_sizes; (void)n_in; (void)out_size; (void)ws_size;
  const float* x   = (const float*)d_in[0];
  const float* u0  = (const float*)d_in[1];
  const int*   ei  = (const int*)d_in[2];
  const float* w1W = (const float*)d_in[3];
  const float* w1b = (const float*)d_in[4];
  const float* m1W = (const float*)d_in[5];
  const float* m1b = (const float*)d_in[6];
  const float* m2W = (const float*)d_in[7];
  const float* m2b = (const float*)d_in[8];
  const float* m3W = (const float*)d_in[9];
  const float* m3b = (const float*)d_in[10];
  const float* w2W = (const float*)d_in[11];
  const float* w2b = (const float*)d_in[12];
  const int* esrc = ei;        // edge_index[0]
  const int* edst = ei + NE;   // edge_index[1]

  char* p = (char*)d_ws;
  auto carve = [&](size_t bytes) { char* r = p; p += (bytes + 255) & ~(size_t)255; return r; };
  float*          xw      = (float*)carve((size_t)NN * CO * 4);        // 25.6 MB
  unsigned short* ubf     = (unsigned short*)carve((size_t)NN * CO * 2); // 12.8 MB
  unsigned short* agg     = (unsigned short*)carve((size_t)NN * CO * 2); // 12.8 MB
  unsigned short* xb      = (unsigned short*)carve((size_t)NN * CI * 2); // 6.4 MB
  unsigned short* wbf     = (unsigned short*)carve((size_t)57344 * 2);
  int*            row_off = (int*)carve((size_t)(NN + 1) * 4);
  int*            deg     = (int*)carve((size_t)NN * 4);
  int*            cursor  = (int*)carve((size_t)NN * 4);
  int*            ssrc    = (int*)carve((size_t)NE * 4);               // 3.2 MB
  float*          g       = (float*)carve(128 * 4);

  hipMemsetAsync(deg, 0, (size_t)NN * 4, stream);
  hipMemsetAsync(cursor, 0, (size_t)NN * 4, stream);
  hipMemsetAsync(g, 0, 128 * 4, stream);

  k_count<<<(NE + 255) / 256, 256, 0, stream>>>(edst, deg);
  k_scan<<<1, 1024, 0, stream>>>(deg, row_off);
  k_fill<<<(NE + 255) / 256, 256, 0, stream>>>(esrc, edst, row_off, cursor, ssrc);
  k_cvt_w<<<(57344 + 255) / 256, 256, 0, stream>>>(w1W, m1W, m2W, m3W, wbf);
  k_cvt_x<<<(NN * CI + 255) / 256, 256, 0, stream>>>(x, xb);

  const int GB = (NN + 63) / 64;
  // xw = x @ w1^T + b1  (fp32 out, computed once)
  k_gemm<64, 2><<<GB, 256, 0, stream>>>(xb, wbf, w1b, nullptr, xw, nullptr);

  const unsigned short* Wm1 = wbf + 8192;
  const unsigned short* Wm2 = wbf + 8192 + 16384;
  const unsigned short* Wm3 = wbf + 8192 + 2 * 16384;
  for (int it = 0; it < 4; ++it) {
    k_gather<<<NN, 64, 0, stream>>>(row_off, ssrc, u0, ubf, it == 0 ? 1 : 0, agg);
    k_gemm<128, 0><<<GB, 256, 0, stream>>>(agg, Wm1, m1b, agg, nullptr, nullptr);  // in-place: block reads its rows before writing them
    k_gemm<128, 0><<<GB, 256, 0, stream>>>(agg, Wm2, m2b, agg, nullptr, nullptr);
    k_gemm<128, 1><<<GB, 256, 0, stream>>>(agg, Wm3, m3b, ubf, nullptr, xw);       // u = relu(xw + tanh(...))
  }

  k_reduce<<<256, 256, 0, stream>>>(ubf, g);
  k_final<<<1, 128, 0, stream>>>(g, w2W, w2b, (float*)d_out);
}

// Round 2
// 650.954 us; speedup vs baseline: 1.1597x; 1.1597x over previous
//
#include <hip/hip_runtime.h>
#include <hip/hip_bf16.h>

#define NN 50000
#define NE 800000
#define CI 64
#define CO 128
#define SCANB 49   // ceil(NN/1024)

typedef __attribute__((ext_vector_type(8))) short bf16x8;
typedef __attribute__((ext_vector_type(4))) float f32x4;

__device__ __forceinline__ unsigned short f2bf(float f) {
  unsigned int u = __float_as_uint(f);
  u += 0x7fffu + ((u >> 16) & 1u);   // RNE; inputs are finite
  return (unsigned short)(u >> 16);
}
__device__ __forceinline__ float bf2f_lo(unsigned int p) { return __uint_as_float(p << 16); }
__device__ __forceinline__ float bf2f_hi(unsigned int p) { return __uint_as_float(p & 0xffff0000u); }

// ---------------- CSR build ----------------
__global__ void k_count(const int* __restrict__ dst, int* __restrict__ deg) {
  int e = blockIdx.x * blockDim.x + threadIdx.x;
  if (e < NE) atomicAdd(&deg[dst[e]], 1);
}

// phase 1: per-block (1024 elems) sums
__global__ __launch_bounds__(256) void k_scan1(const int* __restrict__ deg, int* __restrict__ bsum) {
  int i0 = blockIdx.x * 1024 + threadIdx.x * 4;
  int s = 0;
#pragma unroll
  for (int j = 0; j < 4; ++j) { int i = i0 + j; if (i < NN) s += deg[i]; }
#pragma unroll
  for (int off = 32; off; off >>= 1) s += __shfl_down(s, off);
  __shared__ int ws[4];
  if ((threadIdx.x & 63) == 0) ws[threadIdx.x >> 6] = s;
  __syncthreads();
  if (threadIdx.x == 0) bsum[blockIdx.x] = ws[0] + ws[1] + ws[2] + ws[3];
}

// phase 2: exclusive scan of the 49 block sums (single wave)
__global__ __launch_bounds__(64) void k_scan2(const int* __restrict__ bsum, int* __restrict__ boff) {
  int t = threadIdx.x;
  int v = (t < SCANB) ? bsum[t] : 0;
  int incl = v;
#pragma unroll
  for (int off = 1; off < 64; off <<= 1) {
    int o = __shfl_up(incl, off);
    if (t >= off) incl += o;
  }
  if (t < SCANB) boff[t] = incl - v;
}

// phase 3: apply
__global__ __launch_bounds__(256) void k_scan3(const int* __restrict__ deg, const int* __restrict__ boff,
                                               int* __restrict__ row_off) {
  int b = blockIdx.x;
  int i0 = b * 1024 + threadIdx.x * 4;
  int v[4]; int tsum = 0;
#pragma unroll
  for (int j = 0; j < 4; ++j) { int i = i0 + j; v[j] = (i < NN) ? deg[i] : 0; tsum += v[j]; }
  int incl = tsum;
#pragma unroll
  for (int off = 1; off < 64; off <<= 1) {
    int o = __shfl_up(incl, off);
    if ((threadIdx.x & 63) >= (unsigned)off) incl += o;
  }
  __shared__ int ws[4];
  int w = threadIdx.x >> 6;
  if ((threadIdx.x & 63) == 63) ws[w] = incl;
  __syncthreads();
  int wbase = 0;
  for (int k = 0; k < 4; ++k) if (k < w) wbase += ws[k];
  int excl = boff[b] + wbase + incl - tsum;
#pragma unroll
  for (int j = 0; j < 4; ++j) { int i = i0 + j; if (i < NN) row_off[i] = excl; excl += v[j]; }
  if (b == 0 && threadIdx.x == 0) row_off[NN] = NE;
}

__global__ void k_fill(const int* __restrict__ src, const int* __restrict__ dst,
                       const int* __restrict__ row_off, int* __restrict__ cursor,
                       int* __restrict__ ssrc) {
  int e = blockIdx.x * blockDim.x + threadIdx.x;
  if (e < NE) {
    int d = dst[e];
    int pos = atomicAdd(&cursor[d], 1);
    ssrc[row_off[d] + pos] = src[e];
  }
}

// ---------------- bf16 conversions ----------------
__global__ void k_cvt_w(const float* __restrict__ w1, const float* __restrict__ m1,
                        const float* __restrict__ m2, const float* __restrict__ m3,
                        unsigned short* __restrict__ o) {
  int i = blockIdx.x * blockDim.x + threadIdx.x;
  if (i >= 57344) return;
  float v;
  if (i < 8192) v = w1[i];
  else if (i < 24576) v = m1[i - 8192];
  else if (i < 40960) v = m2[i - 24576];
  else v = m3[i - 40960];
  o[i] = f2bf(v);
}

// fp32 -> bf16, 4 elems/thread
__global__ void k_cvt4(const float* __restrict__ in, unsigned short* __restrict__ out, int n4) {
  int i = blockIdx.x * blockDim.x + threadIdx.x;
  if (i >= n4) return;
  float4 v = *(const float4*)(in + i * 4);
  ushort2 lo = { f2bf(v.x), f2bf(v.y) };
  ushort2 hi = { f2bf(v.z), f2bf(v.w) };
  *(ushort2*)(out + i * 4) = lo;
  *(ushort2*)(out + i * 4 + 2) = hi;
}

// ---------------- CSR gather (segment_sum), bf16 in/out ----------------
// 4 waves/block, one node per wave, __shfl edge broadcast
__global__ __launch_bounds__(256) void k_gather(const int* __restrict__ row_off,
    const int* __restrict__ ssrc, const unsigned short* __restrict__ ubf,
    unsigned short* __restrict__ agg) {
  int node = blockIdx.x * 4 + (threadIdx.x >> 6);
  if (node >= NN) return;               // uniform per wave
  int lane = threadIdx.x & 63;
  int beg = row_off[node], end = row_off[node + 1];
  float a0 = 0.f, a1 = 0.f;
  for (int base = beg; base < end; base += 64) {
    int cnt = min(64, end - base);
    int sid = (base + lane < end) ? ssrc[base + lane] : 0;
    for (int j = 0; j < cnt; ++j) {
      int s = __shfl(sid, j);
      unsigned int p = *(const unsigned int*)(ubf + (size_t)s * CO + lane * 2);
      a0 += bf2f_lo(p); a1 += bf2f_hi(p);
    }
  }
  unsigned int packed = ((unsigned int)f2bf(a1) << 16) | (unsigned int)f2bf(a0);
  *(unsigned int*)(agg + (size_t)node * CO + lane * 2) = packed;
}

// ---------------- xw = x @ w1^T + b1 (fp32 out, once) ----------------
__global__ __launch_bounds__(256) void k_xw(const unsigned short* __restrict__ A,
    const unsigned short* __restrict__ W, const float* __restrict__ bias,
    float* __restrict__ outf) {
  int wave = threadIdx.x >> 6, lane = threadIdx.x & 63;
  int m = lane & 15, q = lane >> 4;
  int row0 = blockIdx.x * 64 + wave * 16;
  int arow = row0 + m; if (arow >= NN) arow = NN - 1;
  const unsigned short* Ar = A + (size_t)arow * CI;
  f32x4 acc[8];
#pragma unroll
  for (int tt = 0; tt < 8; ++tt) acc[tt] = (f32x4){0.f, 0.f, 0.f, 0.f};
#pragma unroll
  for (int ks = 0; ks < CI; ks += 32) {
    bf16x8 a = *(const bf16x8*)(Ar + ks + q * 8);
#pragma unroll
    for (int tt = 0; tt < 8; ++tt) {
      bf16x8 b = *(const bf16x8*)(W + (size_t)(tt * 16 + m) * CI + ks + q * 8);
      acc[tt] = __builtin_amdgcn_mfma_f32_16x16x32_bf16(a, b, acc[tt], 0, 0, 0);
    }
  }
#pragma unroll
  for (int tt = 0; tt < 8; ++tt) {
    int o = tt * 16 + m;
    float bv = bias[o];
#pragma unroll
    for (int r = 0; r < 4; ++r) {
      int node = row0 + q * 4 + r;
      if (node < NN) outf[(size_t)node * CO + o] = acc[tt][r] + bv;
    }
  }
}

// ---------------- fused 3-layer MLP + epilogue ----------------
// u = relu(xw + tanh(relu(relu(agg@W1^T+b1)@W2^T+b2)@W3^T+b3))
// per wave: 16 nodes x full 128 channels; C->A layout via wave-private LDS (no barriers)
__global__ __launch_bounds__(256) void k_mlp(const unsigned short* __restrict__ agg,
    const unsigned short* __restrict__ W1, const unsigned short* __restrict__ W2,
    const unsigned short* __restrict__ W3,
    const float* __restrict__ b1, const float* __restrict__ b2, const float* __restrict__ b3,
    const float* __restrict__ xw, unsigned short* __restrict__ uout) {
  constexpr int SP = 136;                       // elems; 272 B row, 16B-aligned, bank-spread
  __shared__ unsigned short lds[4 * 16 * SP];
  int wave = threadIdx.x >> 6, lane = threadIdx.x & 63;
  int m = lane & 15, q = lane >> 4;
  int row0 = blockIdx.x * 64 + wave * 16;
  unsigned short* L = lds + wave * 16 * SP;
  int arow = row0 + m; if (arow >= NN) arow = NN - 1;
  const unsigned short* Ar = agg + (size_t)arow * CO;

  f32x4 acc[8];
  // ---- layer 1: A from global ----
#pragma unroll
  for (int tt = 0; tt < 8; ++tt) acc[tt] = (f32x4){0.f, 0.f, 0.f, 0.f};
#pragma unroll
  for (int ks = 0; ks < CO; ks += 32) {
    bf16x8 a = *(const bf16x8*)(Ar + ks + q * 8);
#pragma unroll
    for (int tt = 0; tt < 8; ++tt) {
      bf16x8 b = *(const bf16x8*)(W1 + (size_t)(tt * 16 + m) * CO + ks + q * 8);
      acc[tt] = __builtin_amdgcn_mfma_f32_16x16x32_bf16(a, b, acc[tt], 0, 0, 0);
    }
  }
#pragma unroll
  for (int tt = 0; tt < 8; ++tt) {
    float bv = b1[tt * 16 + m];
#pragma unroll
    for (int r = 0; r < 4; ++r)
      L[(q * 4 + r) * SP + tt * 16 + m] = f2bf(fmaxf(acc[tt][r] + bv, 0.f));
  }
  // ---- layer 2: A from LDS (in-order DS pipe; wave-private region, no barrier) ----
#pragma unroll
  for (int tt = 0; tt < 8; ++tt) acc[tt] = (f32x4){0.f, 0.f, 0.f, 0.f};
#pragma unroll
  for (int ks = 0; ks < CO; ks += 32) {
    bf16x8 a = *(const bf16x8*)(L + m * SP + ks + q * 8);
#pragma unroll
    for (int tt = 0; tt < 8; ++tt) {
      bf16x8 b = *(const bf16x8*)(W2 + (size_t)(tt * 16 + m) * CO + ks + q * 8);
      acc[tt] = __builtin_amdgcn_mfma_f32_16x16x32_bf16(a, b, acc[tt], 0, 0, 0);
    }
  }
#pragma unroll
  for (int tt = 0; tt < 8; ++tt) {
    float bv = b2[tt * 16 + m];
#pragma unroll
    for (int r = 0; r < 4; ++r)
      L[(q * 4 + r) * SP + tt * 16 + m] = f2bf(fmaxf(acc[tt][r] + bv, 0.f));
  }
  // ---- layer 3 ----
#pragma unroll
  for (int tt = 0; tt < 8; ++tt) acc[tt] = (f32x4){0.f, 0.f, 0.f, 0.f};
#pragma unroll
  for (int ks = 0; ks < CO; ks += 32) {
    bf16x8 a = *(const bf16x8*)(L + m * SP + ks + q * 8);
#pragma unroll
    for (int tt = 0; tt < 8; ++tt) {
      bf16x8 b = *(const bf16x8*)(W3 + (size_t)(tt * 16 + m) * CO + ks + q * 8);
      acc[tt] = __builtin_amdgcn_mfma_f32_16x16x32_bf16(a, b, acc[tt], 0, 0, 0);
    }
  }
  // epilogue: tanh, +xw, relu -> LDS
#pragma unroll
  for (int tt = 0; tt < 8; ++tt) {
    float bv = b3[tt * 16 + m];
#pragma unroll
    for (int r = 0; r < 4; ++r) {
      int node = row0 + q * 4 + r; if (node >= NN) node = NN - 1;
      float v = acc[tt][r] + bv;
      float e = __expf(2.f * v);
      v = 1.f - 2.f / (e + 1.f);                         // tanh
      v = fmaxf(xw[(size_t)node * CO + tt * 16 + m] + v, 0.f);
      L[(q * 4 + r) * SP + tt * 16 + m] = f2bf(v);
    }
  }
  // packed store: lane -> node lane>>2, 16B chunk (lane&3), 4 rounds
  int ln = lane >> 2, lc = lane & 3;
  int gnode = row0 + ln;
  if (gnode < NN) {
#pragma unroll
    for (int rnd = 0; rnd < 4; ++rnd) {
      bf16x8 vv = *(const bf16x8*)(L + ln * SP + rnd * 32 + lc * 8);
      *(bf16x8*)(uout + (size_t)gnode * CO + rnd * 32 + lc * 8) = vv;
    }
  }
}

// ---------------- final readout ----------------
__global__ __launch_bounds__(256) void k_reduce(const unsigned short* __restrict__ u,
                                                float* __restrict__ g) {
  int ch2 = threadIdx.x & 63;
  int sub = threadIdx.x >> 6;
  float a0 = 0.f, a1 = 0.f;
  for (int n = blockIdx.x * 4 + sub; n < NN; n += gridDim.x * 4) {
    unsigned int p = *(const unsigned int*)(u + (size_t)n * CO + ch2 * 2);
    a0 += bf2f_lo(p); a1 += bf2f_hi(p);
  }
  __shared__ float s0[256], s1[256];
  s0[threadIdx.x] = a0; s1[threadIdx.x] = a1;
  __syncthreads();
  if (sub == 0) {
    a0 = s0[ch2] + s0[64 + ch2] + s0[128 + ch2] + s0[192 + ch2];
    a1 = s1[ch2] + s1[64 + ch2] + s1[128 + ch2] + s1[192 + ch2];
    atomicAdd(&g[ch2 * 2], a0);
    atomicAdd(&g[ch2 * 2 + 1], a1);
  }
}

__global__ void k_final(const float* __restrict__ g, const float* __restrict__ w2,
                        const float* __restrict__ b2, float* __restrict__ outp) {
  __shared__ float sg[128];
  if (threadIdx.x < 128) sg[threadIdx.x] = g[threadIdx.x];
  __syncthreads();
  int j = threadIdx.x;
  if (j < 128) {
    float acc = b2[j];
    for (int c = 0; c < 128; ++c) acc += sg[c] * w2[j * 128 + c];
    outp[j] = acc;
  }
}

extern "C" void kernel_launch(void* const* d_in, const int* in_sizes, int n_in,
                              void* d_out, int out_size, void* d_ws, size_t ws_size,
                              hipStream_t stream) {
  (void)in_sizes; (void)n_in; (void)out_size; (void)ws_size;
  const float* x   = (const float*)d_in[0];
  const float* u0  = (const float*)d_in[1];
  const int*   ei  = (const int*)d_in[2];
  const float* w1W = (const float*)d_in[3];
  const float* w1b = (const float*)d_in[4];
  const float* m1W = (const float*)d_in[5];
  const float* m1b = (const float*)d_in[6];
  const float* m2W = (const float*)d_in[7];
  const float* m2b = (const float*)d_in[8];
  const float* m3W = (const float*)d_in[9];
  const float* m3b = (const float*)d_in[10];
  const float* w2W = (const float*)d_in[11];
  const float* w2b = (const float*)d_in[12];
  const int* esrc = ei;
  const int* edst = ei + NE;

  char* p = (char*)d_ws;
  auto carve = [&](size_t bytes) { char* r = p; p += (bytes + 255) & ~(size_t)255; return r; };
  float*          xw      = (float*)carve((size_t)NN * CO * 4);
  unsigned short* ubf     = (unsigned short*)carve((size_t)NN * CO * 2);
  unsigned short* agg     = (unsigned short*)carve((size_t)NN * CO * 2);
  unsigned short* xb      = (unsigned short*)carve((size_t)NN * CI * 2);
  unsigned short* wbf     = (unsigned short*)carve((size_t)57344 * 2);
  int*            row_off = (int*)carve((size_t)(NN + 1) * 4);
  int*            deg     = (int*)carve((size_t)NN * 4);
  int*            cursor  = (int*)carve((size_t)NN * 4);
  int*            ssrc    = (int*)carve((size_t)NE * 4);
  int*            bsum    = (int*)carve((size_t)SCANB * 4);
  int*            boff    = (int*)carve((size_t)SCANB * 4);
  float*          g       = (float*)carve(128 * 4);

  hipMemsetAsync(deg, 0, (size_t)NN * 4, stream);
  hipMemsetAsync(cursor, 0, (size_t)NN * 4, stream);
  hipMemsetAsync(g, 0, 128 * 4, stream);

  k_count<<<(NE + 255) / 256, 256, 0, stream>>>(edst, deg);
  k_scan1<<<SCANB, 256, 0, stream>>>(deg, bsum);
  k_scan2<<<1, 64, 0, stream>>>(bsum, boff);
  k_scan3<<<SCANB, 256, 0, stream>>>(deg, boff, row_off);
  k_fill<<<(NE + 255) / 256, 256, 0, stream>>>(esrc, edst, row_off, cursor, ssrc);
  k_cvt_w<<<(57344 + 255) / 256, 256, 0, stream>>>(w1W, m1W, m2W, m3W, wbf);
  k_cvt4<<<(NN * CI / 4 + 255) / 256, 256, 0, stream>>>(x, xb, NN * CI / 4);
  k_cvt4<<<(NN * CO / 4 + 255) / 256, 256, 0, stream>>>(u0, ubf, NN * CO / 4);

  const int GB = (NN + 63) / 64;
  k_xw<<<GB, 256, 0, stream>>>(xb, wbf, w1b, xw);

  const unsigned short* Wm1 = wbf + 8192;
  const unsigned short* Wm2 = wbf + 8192 + 16384;
  const unsigned short* Wm3 = wbf + 8192 + 2 * 16384;
  for (int it = 0; it < 4; ++it) {
    k_gather<<<(NN + 3) / 4, 256, 0, stream>>>(row_off, ssrc, ubf, agg);
    k_mlp<<<GB, 256, 0, stream>>>(agg, Wm1, Wm2, Wm3, m1b, m2b, m3b, xw, ubf);
  }

  k_reduce<<<256, 256, 0, stream>>>(ubf, g);
  k_final<<<1, 128, 0, stream>>>(g, w2W, w2b, (float*)d_out);
}

// Round 3
// 534.188 us; speedup vs baseline: 1.4131x; 1.2186x over previous
//
#include <hip/hip_runtime.h>
#include <hip/hip_bf16.h>

#define NN 50000
#define NE 800000
#define CI 64
#define CO 128
#define SCANB 49   // ceil(NN/1024)

typedef __attribute__((ext_vector_type(8))) short bf16x8;
typedef __attribute__((ext_vector_type(4))) float f32x4;

__device__ __forceinline__ unsigned short f2bf(float f) {
  unsigned int u = __float_as_uint(f);
  u += 0x7fffu + ((u >> 16) & 1u);   // RNE; inputs are finite
  return (unsigned short)(u >> 16);
}
__device__ __forceinline__ float bf2f_lo(unsigned int p) { return __uint_as_float(p << 16); }
__device__ __forceinline__ float bf2f_hi(unsigned int p) { return __uint_as_float(p & 0xffff0000u); }
__device__ __forceinline__ unsigned int pk2(float lo, float hi) {
  return ((unsigned int)f2bf(hi) << 16) | (unsigned int)f2bf(lo);
}

// ---------------- CSR build ----------------
__global__ void k_count(const int* __restrict__ dst, int* __restrict__ deg) {
  int e = blockIdx.x * blockDim.x + threadIdx.x;
  if (e < NE) atomicAdd(&deg[dst[e]], 1);
}

__global__ __launch_bounds__(256) void k_scan1(const int* __restrict__ deg, int* __restrict__ bsum) {
  int i0 = blockIdx.x * 1024 + threadIdx.x * 4;
  int s = 0;
#pragma unroll
  for (int j = 0; j < 4; ++j) { int i = i0 + j; if (i < NN) s += deg[i]; }
#pragma unroll
  for (int off = 32; off; off >>= 1) s += __shfl_down(s, off);
  __shared__ int ws[4];
  if ((threadIdx.x & 63) == 0) ws[threadIdx.x >> 6] = s;
  __syncthreads();
  if (threadIdx.x == 0) bsum[blockIdx.x] = ws[0] + ws[1] + ws[2] + ws[3];
}

__global__ __launch_bounds__(64) void k_scan2(const int* __restrict__ bsum, int* __restrict__ boff) {
  int t = threadIdx.x;
  int v = (t < SCANB) ? bsum[t] : 0;
  int incl = v;
#pragma unroll
  for (int off = 1; off < 64; off <<= 1) {
    int o = __shfl_up(incl, off);
    if (t >= off) incl += o;
  }
  if (t < SCANB) boff[t] = incl - v;
}

__global__ __launch_bounds__(256) void k_scan3(const int* __restrict__ deg, const int* __restrict__ boff,
                                               int* __restrict__ row_off) {
  int b = blockIdx.x;
  int i0 = b * 1024 + threadIdx.x * 4;
  int v[4]; int tsum = 0;
#pragma unroll
  for (int j = 0; j < 4; ++j) { int i = i0 + j; v[j] = (i < NN) ? deg[i] : 0; tsum += v[j]; }
  int incl = tsum;
#pragma unroll
  for (int off = 1; off < 64; off <<= 1) {
    int o = __shfl_up(incl, off);
    if ((threadIdx.x & 63) >= (unsigned)off) incl += o;
  }
  __shared__ int ws[4];
  int w = threadIdx.x >> 6;
  if ((threadIdx.x & 63) == 63) ws[w] = incl;
  __syncthreads();
  int wbase = 0;
  for (int k = 0; k < 4; ++k) if (k < w) wbase += ws[k];
  int excl = boff[b] + wbase + incl - tsum;
#pragma unroll
  for (int j = 0; j < 4; ++j) { int i = i0 + j; if (i < NN) row_off[i] = excl; excl += v[j]; }
  if (b == 0 && threadIdx.x == 0) row_off[NN] = NE;
}

__global__ void k_fill(const int* __restrict__ src, const int* __restrict__ dst,
                       const int* __restrict__ row_off, int* __restrict__ cursor,
                       int* __restrict__ ssrc) {
  int e = blockIdx.x * blockDim.x + threadIdx.x;
  if (e < NE) {
    int d = dst[e];
    int pos = atomicAdd(&cursor[d], 1);
    ssrc[row_off[d] + pos] = src[e];
  }
}

// ---------------- bf16 conversions ----------------
__global__ void k_cvt_w(const float* __restrict__ w1, const float* __restrict__ m1,
                        const float* __restrict__ m2, const float* __restrict__ m3,
                        unsigned short* __restrict__ o) {
  int i = blockIdx.x * blockDim.x + threadIdx.x;
  if (i >= 57344) return;
  float v;
  if (i < 8192) v = w1[i];
  else if (i < 24576) v = m1[i - 8192];
  else if (i < 40960) v = m2[i - 24576];
  else v = m3[i - 40960];
  o[i] = f2bf(v);
}

__global__ void k_cvt4(const float* __restrict__ in, unsigned short* __restrict__ out, int n4) {
  int i = blockIdx.x * blockDim.x + threadIdx.x;
  if (i >= n4) return;
  float4 v = *(const float4*)(in + i * 4);
  ushort2 lo = { f2bf(v.x), f2bf(v.y) };
  ushort2 hi = { f2bf(v.z), f2bf(v.w) };
  *(ushort2*)(out + i * 4) = lo;
  *(ushort2*)(out + i * 4 + 2) = hi;
}

// ---------------- CSR gather (segment_sum) ----------------
// 4 waves/block, one node per wave. b128 loads: one wave-instruction fetches
// 4 (bf16) / 2 (fp32) full source rows. Cross-edge-group reduce via shfl_xor.
__global__ __launch_bounds__(256) void k_gather(const int* __restrict__ row_off,
    const int* __restrict__ ssrc, const float* __restrict__ u32,
    const unsigned short* __restrict__ ubf, int first,
    unsigned short* __restrict__ agg) {
  int node = blockIdx.x * 4 + (threadIdx.x >> 6);
  int lane = threadIdx.x & 63;
  int beg = row_off[node], end = row_off[node + 1];
  if (first) {
    // fp32 rows (512 B): eg in [0,2) edge-groups, c in [0,32) 16B-chunks
    int eg = lane >> 5, c = lane & 31;
    float a0 = 0.f, a1 = 0.f, a2 = 0.f, a3 = 0.f;
    for (int base = beg; base < end; base += 64) {
      int e = base + lane;
      int sid = (e < end) ? ssrc[e] : 0;
      int cnt = min(64, end - base);
      int j = 0;
      for (; j + 2 <= cnt; j += 2) {
        int s = __shfl(sid, j + eg);
        float4 v = *(const float4*)(u32 + (size_t)s * CO + c * 4);
        a0 += v.x; a1 += v.y; a2 += v.z; a3 += v.w;
      }
      if (j < cnt) {                       // 1 leftover edge
        int s = __shfl(sid, j);
        if (eg == 0) {
          float4 v = *(const float4*)(u32 + (size_t)s * CO + c * 4);
          a0 += v.x; a1 += v.y; a2 += v.z; a3 += v.w;
        }
      }
    }
    a0 += __shfl_xor(a0, 32); a1 += __shfl_xor(a1, 32);
    a2 += __shfl_xor(a2, 32); a3 += __shfl_xor(a3, 32);
    if (lane < 32) {
      uint2 o = { pk2(a0, a1), pk2(a2, a3) };
      *(uint2*)(agg + (size_t)node * CO + c * 4) = o;
    }
  } else {
    // bf16 rows (256 B): eg in [0,4) edge-groups, c in [0,16) 16B-chunks
    int eg = lane >> 4, c = lane & 15;
    float a[8];
#pragma unroll
    for (int i = 0; i < 8; ++i) a[i] = 0.f;
    for (int base = beg; base < end; base += 64) {
      int e = base + lane;
      int sid = (e < end) ? ssrc[e] : 0;
      int cnt = min(64, end - base);
      int j = 0;
#pragma unroll 2
      for (; j + 4 <= cnt; j += 4) {
        int s = __shfl(sid, j + eg);
        uint4 r = *(const uint4*)(ubf + (size_t)s * CO + c * 8);
        a[0] += bf2f_lo(r.x); a[1] += bf2f_hi(r.x);
        a[2] += bf2f_lo(r.y); a[3] += bf2f_hi(r.y);
        a[4] += bf2f_lo(r.z); a[5] += bf2f_hi(r.z);
        a[6] += bf2f_lo(r.w); a[7] += bf2f_hi(r.w);
      }
      if (j < cnt) {                       // 1..3 leftover edges
        int rem = cnt - j;
        int s = __shfl(sid, j + min(eg, rem - 1));
        if (eg < rem) {
          uint4 r = *(const uint4*)(ubf + (size_t)s * CO + c * 8);
          a[0] += bf2f_lo(r.x); a[1] += bf2f_hi(r.x);
          a[2] += bf2f_lo(r.y); a[3] += bf2f_hi(r.y);
          a[4] += bf2f_lo(r.z); a[5] += bf2f_hi(r.z);
          a[6] += bf2f_lo(r.w); a[7] += bf2f_hi(r.w);
        }
      }
    }
#pragma unroll
    for (int i = 0; i < 8; ++i) { a[i] += __shfl_xor(a[i], 16); a[i] += __shfl_xor(a[i], 32); }
    if (lane < 16) {
      uint4 o;
      o.x = pk2(a[0], a[1]); o.y = pk2(a[2], a[3]);
      o.z = pk2(a[4], a[5]); o.w = pk2(a[6], a[7]);
      *(uint4*)(agg + (size_t)node * CO + c * 8) = o;
    }
  }
}

// ---------------- xw = bf16(x @ w1^T + b1), computed once ----------------
__global__ __launch_bounds__(256) void k_xw(const unsigned short* __restrict__ A,
    const unsigned short* __restrict__ W, const float* __restrict__ bias,
    unsigned short* __restrict__ xwb) {
  int wave = threadIdx.x >> 6, lane = threadIdx.x & 63;
  int m = lane & 15, q = lane >> 4;
  int row0 = blockIdx.x * 64 + wave * 16;
  int arow = row0 + m; if (arow >= NN) arow = NN - 1;
  const unsigned short* Ar = A + (size_t)arow * CI;
  f32x4 acc[8];
#pragma unroll
  for (int tt = 0; tt < 8; ++tt) acc[tt] = (f32x4){0.f, 0.f, 0.f, 0.f};
#pragma unroll
  for (int ks = 0; ks < CI; ks += 32) {
    bf16x8 a = *(const bf16x8*)(Ar + ks + q * 8);
#pragma unroll
    for (int tt = 0; tt < 8; ++tt) {
      bf16x8 b = *(const bf16x8*)(W + (size_t)(tt * 16 + m) * CI + ks + q * 8);
      acc[tt] = __builtin_amdgcn_mfma_f32_16x16x32_bf16(a, b, acc[tt], 0, 0, 0);
    }
  }
#pragma unroll
  for (int tt = 0; tt < 8; ++tt) {
    int o = tt * 16 + m;
    float bv = bias[o];
#pragma unroll
    for (int r = 0; r < 4; ++r) {
      int node = row0 + q * 4 + r;
      if (node < NN) xwb[(size_t)node * CO + o] = f2bf(acc[tt][r] + bv);
    }
  }
}

// ---------------- fused 3-layer MLP + epilogue ----------------
// 128-thread blocks, 2 waves; each wave: 32 nodes (two 16-row A-groups sharing
// every B-fragment) x full 128 channels. C->A transform via wave-private LDS.
// Epilogue: tanh->LDS, then fused b128 read of LDS h + bf16 xw, add, relu, store.
__global__ __launch_bounds__(128) void k_mlp(const unsigned short* __restrict__ agg,
    const unsigned short* __restrict__ W1, const unsigned short* __restrict__ W2,
    const unsigned short* __restrict__ W3,
    const float* __restrict__ b1, const float* __restrict__ b2, const float* __restrict__ b3,
    const unsigned short* __restrict__ xwb, unsigned short* __restrict__ uout) {
  constexpr int SP = 136;                 // 272 B row stride, 16B-aligned
  __shared__ unsigned short lds[2 * 32 * SP];
  int wave = threadIdx.x >> 6, lane = threadIdx.x & 63;
  int m = lane & 15, q = lane >> 4;
  int row0 = blockIdx.x * 64 + wave * 32;
  unsigned short* L = lds + wave * 32 * SP;
  int ar0 = row0 + m;      if (ar0 >= NN) ar0 = NN - 1;   // clamped loads; stores guarded
  int ar1 = row0 + 16 + m; if (ar1 >= NN) ar1 = NN - 1;
  const unsigned short* A0p = agg + (size_t)ar0 * CO;
  const unsigned short* A1p = agg + (size_t)ar1 * CO;

  f32x4 acc[2][8];
#pragma unroll
  for (int g = 0; g < 2; ++g)
#pragma unroll
    for (int t = 0; t < 8; ++t) acc[g][t] = (f32x4){0.f, 0.f, 0.f, 0.f};

  // ---- layer 1: A from global, B shared across both A-groups ----
#pragma unroll
  for (int ks = 0; ks < CO; ks += 32) {
    bf16x8 a0 = *(const bf16x8*)(A0p + ks + q * 8);
    bf16x8 a1 = *(const bf16x8*)(A1p + ks + q * 8);
#pragma unroll
    for (int t = 0; t < 8; ++t) {
      bf16x8 b = *(const bf16x8*)(W1 + (size_t)(t * 16 + m) * CO + ks + q * 8);
      acc[0][t] = __builtin_amdgcn_mfma_f32_16x16x32_bf16(a0, b, acc[0][t], 0, 0, 0);
      acc[1][t] = __builtin_amdgcn_mfma_f32_16x16x32_bf16(a1, b, acc[1][t], 0, 0, 0);
    }
  }
#pragma unroll
  for (int t = 0; t < 8; ++t) {
    float bv = b1[t * 16 + m];
#pragma unroll
    for (int g = 0; g < 2; ++g)
#pragma unroll
      for (int r = 0; r < 4; ++r)
        L[(g * 16 + q * 4 + r) * SP + t * 16 + m] = f2bf(fmaxf(acc[g][t][r] + bv, 0.f));
  }
  // ---- layer 2: A from wave-private LDS (in-order DS pipe, no barrier) ----
#pragma unroll
  for (int g = 0; g < 2; ++g)
#pragma unroll
    for (int t = 0; t < 8; ++t) acc[g][t] = (f32x4){0.f, 0.f, 0.f, 0.f};
#pragma unroll
  for (int ks = 0; ks < CO; ks += 32) {
    bf16x8 a0 = *(const bf16x8*)(L + m * SP + ks + q * 8);
    bf16x8 a1 = *(const bf16x8*)(L + (16 + m) * SP + ks + q * 8);
#pragma unroll
    for (int t = 0; t < 8; ++t) {
      bf16x8 b = *(const bf16x8*)(W2 + (size_t)(t * 16 + m) * CO + ks + q * 8);
      acc[0][t] = __builtin_amdgcn_mfma_f32_16x16x32_bf16(a0, b, acc[0][t], 0, 0, 0);
      acc[1][t] = __builtin_amdgcn_mfma_f32_16x16x32_bf16(a1, b, acc[1][t], 0, 0, 0);
    }
  }
#pragma unroll
  for (int t = 0; t < 8; ++t) {
    float bv = b2[t * 16 + m];
#pragma unroll
    for (int g = 0; g < 2; ++g)
#pragma unroll
      for (int r = 0; r < 4; ++r)
        L[(g * 16 + q * 4 + r) * SP + t * 16 + m] = f2bf(fmaxf(acc[g][t][r] + bv, 0.f));
  }
  // ---- layer 3 ----
#pragma unroll
  for (int g = 0; g < 2; ++g)
#pragma unroll
    for (int t = 0; t < 8; ++t) acc[g][t] = (f32x4){0.f, 0.f, 0.f, 0.f};
#pragma unroll
  for (int ks = 0; ks < CO; ks += 32) {
    bf16x8 a0 = *(const bf16x8*)(L + m * SP + ks + q * 8);
    bf16x8 a1 = *(const bf16x8*)(L + (16 + m) * SP + ks + q * 8);
#pragma unroll
    for (int t = 0; t < 8; ++t) {
      bf16x8 b = *(const bf16x8*)(W3 + (size_t)(t * 16 + m) * CO + ks + q * 8);
      acc[0][t] = __builtin_amdgcn_mfma_f32_16x16x32_bf16(a0, b, acc[0][t], 0, 0, 0);
      acc[1][t] = __builtin_amdgcn_mfma_f32_16x16x32_bf16(a1, b, acc[1][t], 0, 0, 0);
    }
  }
  // tanh -> LDS
#pragma unroll
  for (int t = 0; t < 8; ++t) {
    float bv = b3[t * 16 + m];
#pragma unroll
    for (int g = 0; g < 2; ++g)
#pragma unroll
      for (int r = 0; r < 4; ++r) {
        float v = acc[g][t][r] + bv;
        float e = __expf(2.f * v);
        v = 1.f - 2.f / (e + 1.f);        // tanh
        L[(g * 16 + q * 4 + r) * SP + t * 16 + m] = f2bf(v);
      }
  }
  // fused store: u = relu(xw + tanh) with packed b128 traffic
  int ln = lane >> 1, lc = lane & 1;      // node-in-wave, chunk half
  int gnode = row0 + ln;
  if (gnode < NN) {
    const unsigned short* xr = xwb + (size_t)gnode * CO;
    unsigned short* ur = uout + (size_t)gnode * CO;
#pragma unroll
    for (int rnd = 0; rnd < 8; ++rnd) {
      int ch = (rnd * 2 + lc) * 8;
      uint4 h = *(const uint4*)(L + ln * SP + ch);
      uint4 xv = *(const uint4*)(xr + ch);
      uint4 o;
      o.x = pk2(fmaxf(bf2f_lo(h.x) + bf2f_lo(xv.x), 0.f), fmaxf(bf2f_hi(h.x) + bf2f_hi(xv.x), 0.f));
      o.y = pk2(fmaxf(bf2f_lo(h.y) + bf2f_lo(xv.y), 0.f), fmaxf(bf2f_hi(h.y) + bf2f_hi(xv.y), 0.f));
      o.z = pk2(fmaxf(bf2f_lo(h.z) + bf2f_lo(xv.z), 0.f), fmaxf(bf2f_hi(h.z) + bf2f_hi(xv.z), 0.f));
      o.w = pk2(fmaxf(bf2f_lo(h.w) + bf2f_lo(xv.w), 0.f), fmaxf(bf2f_hi(h.w) + bf2f_hi(xv.w), 0.f));
      *(uint4*)(ur + ch) = o;
    }
  }
}

// ---------------- final readout ----------------
__global__ __launch_bounds__(256) void k_reduce(const unsigned short* __restrict__ u,
                                                float* __restrict__ g) {
  int ch2 = threadIdx.x & 63;
  int sub = threadIdx.x >> 6;
  float a0 = 0.f, a1 = 0.f;
  for (int n = blockIdx.x * 4 + sub; n < NN; n += gridDim.x * 4) {
    unsigned int p = *(const unsigned int*)(u + (size_t)n * CO + ch2 * 2);
    a0 += bf2f_lo(p); a1 += bf2f_hi(p);
  }
  __shared__ float s0[256], s1[256];
  s0[threadIdx.x] = a0; s1[threadIdx.x] = a1;
  __syncthreads();
  if (sub == 0) {
    a0 = s0[ch2] + s0[64 + ch2] + s0[128 + ch2] + s0[192 + ch2];
    a1 = s1[ch2] + s1[64 + ch2] + s1[128 + ch2] + s1[192 + ch2];
    atomicAdd(&g[ch2 * 2], a0);
    atomicAdd(&g[ch2 * 2 + 1], a1);
  }
}

__global__ void k_final(const float* __restrict__ g, const float* __restrict__ w2,
                        const float* __restrict__ b2, float* __restrict__ outp) {
  __shared__ float sg[128];
  if (threadIdx.x < 128) sg[threadIdx.x] = g[threadIdx.x];
  __syncthreads();
  int j = threadIdx.x;
  if (j < 128) {
    float acc = b2[j];
    for (int c = 0; c < 128; ++c) acc += sg[c] * w2[j * 128 + c];
    outp[j] = acc;
  }
}

extern "C" void kernel_launch(void* const* d_in, const int* in_sizes, int n_in,
                              void* d_out, int out_size, void* d_ws, size_t ws_size,
                              hipStream_t stream) {
  (void)in_sizes; (void)n_in; (void)out_size; (void)ws_size;
  const float* x   = (const float*)d_in[0];
  const float* u0  = (const float*)d_in[1];
  const int*   ei  = (const int*)d_in[2];
  const float* w1W = (const float*)d_in[3];
  const float* w1b = (const float*)d_in[4];
  const float* m1W = (const float*)d_in[5];
  const float* m1b = (const float*)d_in[6];
  const float* m2W = (const float*)d_in[7];
  const float* m2b = (const float*)d_in[8];
  const float* m3W = (const float*)d_in[9];
  const float* m3b = (const float*)d_in[10];
  const float* w2W = (const float*)d_in[11];
  const float* w2b = (const float*)d_in[12];
  const int* esrc = ei;
  const int* edst = ei + NE;

  char* p = (char*)d_ws;
  auto carve = [&](size_t bytes) { char* r = p; p += (bytes + 255) & ~(size_t)255; return r; };
  unsigned short* xwb     = (unsigned short*)carve((size_t)NN * CO * 2);
  unsigned short* ubf     = (unsigned short*)carve((size_t)NN * CO * 2);
  unsigned short* agg     = (unsigned short*)carve((size_t)NN * CO * 2);
  unsigned short* xb      = (unsigned short*)carve((size_t)NN * CI * 2);
  unsigned short* wbf     = (unsigned short*)carve((size_t)57344 * 2);
  int*            row_off = (int*)carve((size_t)(NN + 1) * 4);
  int*            deg     = (int*)carve((size_t)NN * 4);
  int*            cursor  = (int*)carve((size_t)NN * 4);
  int*            ssrc    = (int*)carve((size_t)NE * 4);
  int*            bsum    = (int*)carve((size_t)SCANB * 4);
  int*            boff    = (int*)carve((size_t)SCANB * 4);
  float*          g       = (float*)carve(128 * 4);

  hipMemsetAsync(deg, 0, (size_t)NN * 4, stream);
  hipMemsetAsync(cursor, 0, (size_t)NN * 4, stream);
  hipMemsetAsync(g, 0, 128 * 4, stream);

  k_count<<<(NE + 255) / 256, 256, 0, stream>>>(edst, deg);
  k_scan1<<<SCANB, 256, 0, stream>>>(deg, bsum);
  k_scan2<<<1, 64, 0, stream>>>(bsum, boff);
  k_scan3<<<SCANB, 256, 0, stream>>>(deg, boff, row_off);
  k_fill<<<(NE + 255) / 256, 256, 0, stream>>>(esrc, edst, row_off, cursor, ssrc);
  k_cvt_w<<<(57344 + 255) / 256, 256, 0, stream>>>(w1W, m1W, m2W, m3W, wbf);
  k_cvt4<<<(NN * CI / 4 + 255) / 256, 256, 0, stream>>>(x, xb, NN * CI / 4);

  k_xw<<<(NN + 63) / 64, 256, 0, stream>>>(xb, wbf, w1b, xwb);

  const unsigned short* Wm1 = wbf + 8192;
  const unsigned short* Wm2 = wbf + 8192 + 16384;
  const unsigned short* Wm3 = wbf + 8192 + 2 * 16384;
  const int GM = (NN + 63) / 64;   // 64 nodes per 128-thread mlp block
  for (int it = 0; it < 4; ++it) {
    k_gather<<<(NN + 3) / 4, 256, 0, stream>>>(row_off, ssrc, u0, ubf, it == 0 ? 1 : 0, agg);
    k_mlp<<<GM, 128, 0, stream>>>(agg, Wm1, Wm2, Wm3, m1b, m2b, m3b, xwb, ubf);
  }

  k_reduce<<<256, 256, 0, stream>>>(ubf, g);
  k_final<<<1, 128, 0, stream>>>(g, w2W, w2b, (float*)d_out);
}

// Round 4
// 509.121 us; speedup vs baseline: 1.4827x; 1.0492x over previous
//
#include <hip/hip_runtime.h>
#include <hip/hip_bf16.h>

#define NN 50000
#define NE 800000
#define CI 64
#define CO 128
#define SCANB 49   // ceil(NN/1024)

typedef __attribute__((ext_vector_type(8))) short bf16x8;
typedef __attribute__((ext_vector_type(4))) float f32x4;

__device__ __forceinline__ unsigned short f2bf(float f) {
  unsigned int u = __float_as_uint(f);
  u += 0x7fffu + ((u >> 16) & 1u);   // RNE; inputs are finite
  return (unsigned short)(u >> 16);
}
__device__ __forceinline__ float bf2f_lo(unsigned int p) { return __uint_as_float(p << 16); }
__device__ __forceinline__ float bf2f_hi(unsigned int p) { return __uint_as_float(p & 0xffff0000u); }
__device__ __forceinline__ unsigned int pk2(float lo, float hi) {
  return ((unsigned int)f2bf(hi) << 16) | (unsigned int)f2bf(lo);
}

// ---------------- CSR build ----------------
__global__ void k_count(const int* __restrict__ dst, int* __restrict__ deg) {
  int e = blockIdx.x * blockDim.x + threadIdx.x;
  if (e < NE) atomicAdd(&deg[dst[e]], 1);
}

__global__ __launch_bounds__(256) void k_scan1(const int* __restrict__ deg, int* __restrict__ bsum) {
  int i0 = blockIdx.x * 1024 + threadIdx.x * 4;
  int s = 0;
#pragma unroll
  for (int j = 0; j < 4; ++j) { int i = i0 + j; if (i < NN) s += deg[i]; }
#pragma unroll
  for (int off = 32; off; off >>= 1) s += __shfl_down(s, off);
  __shared__ int ws[4];
  if ((threadIdx.x & 63) == 0) ws[threadIdx.x >> 6] = s;
  __syncthreads();
  if (threadIdx.x == 0) bsum[blockIdx.x] = ws[0] + ws[1] + ws[2] + ws[3];
}

__global__ __launch_bounds__(64) void k_scan2(const int* __restrict__ bsum, int* __restrict__ boff) {
  int t = threadIdx.x;
  int v = (t < SCANB) ? bsum[t] : 0;
  int incl = v;
#pragma unroll
  for (int off = 1; off < 64; off <<= 1) {
    int o = __shfl_up(incl, off);
    if (t >= off) incl += o;
  }
  if (t < SCANB) boff[t] = incl - v;
}

__global__ __launch_bounds__(256) void k_scan3(const int* __restrict__ deg, const int* __restrict__ boff,
                                               int* __restrict__ row_off) {
  int b = blockIdx.x;
  int i0 = b * 1024 + threadIdx.x * 4;
  int v[4]; int tsum = 0;
#pragma unroll
  for (int j = 0; j < 4; ++j) { int i = i0 + j; v[j] = (i < NN) ? deg[i] : 0; tsum += v[j]; }
  int incl = tsum;
#pragma unroll
  for (int off = 1; off < 64; off <<= 1) {
    int o = __shfl_up(incl, off);
    if ((threadIdx.x & 63) >= (unsigned)off) incl += o;
  }
  __shared__ int ws[4];
  int w = threadIdx.x >> 6;
  if ((threadIdx.x & 63) == 63) ws[w] = incl;
  __syncthreads();
  int wbase = 0;
  for (int k = 0; k < 4; ++k) if (k < w) wbase += ws[k];
  int excl = boff[b] + wbase + incl - tsum;
#pragma unroll
  for (int j = 0; j < 4; ++j) { int i = i0 + j; if (i < NN) row_off[i] = excl; excl += v[j]; }
  if (b == 0 && threadIdx.x == 0) row_off[NN] = NE;
}

__global__ void k_fill(const int* __restrict__ src, const int* __restrict__ dst,
                       const int* __restrict__ row_off, int* __restrict__ cursor,
                       int* __restrict__ ssrc) {
  int e = blockIdx.x * blockDim.x + threadIdx.x;
  if (e < NE) {
    int d = dst[e];
    int pos = atomicAdd(&cursor[d], 1);
    ssrc[row_off[d] + pos] = src[e];
  }
}

// ---------------- bf16 conversions ----------------
__global__ void k_cvt_w(const float* __restrict__ w1, const float* __restrict__ m1,
                        const float* __restrict__ m2, const float* __restrict__ m3,
                        unsigned short* __restrict__ o) {
  int i = blockIdx.x * blockDim.x + threadIdx.x;
  if (i >= 57344) return;
  float v;
  if (i < 8192) v = w1[i];
  else if (i < 24576) v = m1[i - 8192];
  else if (i < 40960) v = m2[i - 24576];
  else v = m3[i - 40960];
  o[i] = f2bf(v);
}

__global__ void k_cvt4(const float* __restrict__ in, unsigned short* __restrict__ out, int n4) {
  int i = blockIdx.x * blockDim.x + threadIdx.x;
  if (i >= n4) return;
  float4 v = *(const float4*)(in + i * 4);
  ushort2 lo = { f2bf(v.x), f2bf(v.y) };
  ushort2 hi = { f2bf(v.z), f2bf(v.w) };
  *(ushort2*)(out + i * 4) = lo;
  *(ushort2*)(out + i * 4 + 2) = hi;
}

// ---------------- CSR gather (segment_sum), bf16 ----------------
// 4 waves/block, one node/wave. eg=lane>>4 edge-group, c=lane&15 16B-chunk:
// one b128 instruction covers 4 full rows. 16-edge batches stage 4 independent
// uint4 loads before consuming -> 4+ loads in flight (latency hiding).
__global__ __launch_bounds__(256) void k_gather(const int* __restrict__ row_off,
    const int* __restrict__ ssrc, const unsigned short* __restrict__ ubf,
    unsigned short* __restrict__ agg) {
  int node = blockIdx.x * 4 + (threadIdx.x >> 6);
  if (node >= NN) return;
  int lane = threadIdx.x & 63;
  int eg = lane >> 4, c = lane & 15;
  int beg = row_off[node], end = row_off[node + 1];
  float a[8];
#pragma unroll
  for (int i = 0; i < 8; ++i) a[i] = 0.f;

#define ADD8(r) { a[0] += bf2f_lo(r.x); a[1] += bf2f_hi(r.x); \
                  a[2] += bf2f_lo(r.y); a[3] += bf2f_hi(r.y); \
                  a[4] += bf2f_lo(r.z); a[5] += bf2f_hi(r.z); \
                  a[6] += bf2f_lo(r.w); a[7] += bf2f_hi(r.w); }

  for (int base = beg; base < end; base += 64) {
    int e = base + lane;
    int sid = (e < end) ? ssrc[e] : 0;
    int cnt = min(64, end - base);
    int j = 0;
    // 16-edge batches: 4 independent staged b128 loads
    for (; j + 16 <= cnt; j += 16) {
      int s0 = __shfl(sid, j + 0 + eg);
      int s1 = __shfl(sid, j + 4 + eg);
      int s2 = __shfl(sid, j + 8 + eg);
      int s3 = __shfl(sid, j + 12 + eg);
      uint4 r0 = *(const uint4*)(ubf + (size_t)s0 * CO + c * 8);
      uint4 r1 = *(const uint4*)(ubf + (size_t)s1 * CO + c * 8);
      uint4 r2 = *(const uint4*)(ubf + (size_t)s2 * CO + c * 8);
      uint4 r3 = *(const uint4*)(ubf + (size_t)s3 * CO + c * 8);
      ADD8(r0); ADD8(r1); ADD8(r2); ADD8(r3);
    }
    // 4-edge quads
    for (; j + 4 <= cnt; j += 4) {
      int s = __shfl(sid, j + eg);
      uint4 r = *(const uint4*)(ubf + (size_t)s * CO + c * 8);
      ADD8(r);
    }
    // 1..3 leftover edges
    if (j < cnt) {
      int rem = cnt - j;
      int s = __shfl(sid, j + min(eg, rem - 1));
      if (eg < rem) {
        uint4 r = *(const uint4*)(ubf + (size_t)s * CO + c * 8);
        ADD8(r);
      }
    }
  }
#undef ADD8
#pragma unroll
  for (int i = 0; i < 8; ++i) { a[i] += __shfl_xor(a[i], 16); a[i] += __shfl_xor(a[i], 32); }
  if (lane < 16) {
    uint4 o;
    o.x = pk2(a[0], a[1]); o.y = pk2(a[2], a[3]);
    o.z = pk2(a[4], a[5]); o.w = pk2(a[6], a[7]);
    *(uint4*)(agg + (size_t)node * CO + c * 8) = o;
  }
}

// ---------------- xw = bf16(x @ w1^T + b1), computed once ----------------
__global__ __launch_bounds__(256) void k_xw(const unsigned short* __restrict__ A,
    const unsigned short* __restrict__ W, const float* __restrict__ bias,
    unsigned short* __restrict__ xwb) {
  int wave = threadIdx.x >> 6, lane = threadIdx.x & 63;
  int m = lane & 15, q = lane >> 4;
  int row0 = blockIdx.x * 64 + wave * 16;
  int arow = row0 + m; if (arow >= NN) arow = NN - 1;
  const unsigned short* Ar = A + (size_t)arow * CI;
  f32x4 acc[8];
#pragma unroll
  for (int tt = 0; tt < 8; ++tt) acc[tt] = (f32x4){0.f, 0.f, 0.f, 0.f};
#pragma unroll
  for (int ks = 0; ks < CI; ks += 32) {
    bf16x8 a = *(const bf16x8*)(Ar + ks + q * 8);
#pragma unroll
    for (int tt = 0; tt < 8; ++tt) {
      bf16x8 b = *(const bf16x8*)(W + (size_t)(tt * 16 + m) * CI + ks + q * 8);
      acc[tt] = __builtin_amdgcn_mfma_f32_16x16x32_bf16(a, b, acc[tt], 0, 0, 0);
    }
  }
#pragma unroll
  for (int tt = 0; tt < 8; ++tt) {
    int o = tt * 16 + m;
    float bv = bias[o];
#pragma unroll
    for (int r = 0; r < 4; ++r) {
      int node = row0 + q * 4 + r;
      if (node < NN) xwb[(size_t)node * CO + o] = f2bf(acc[tt][r] + bv);
    }
  }
}

// ---------------- fused 3-layer MLP + epilogue ----------------
__global__ __launch_bounds__(128) void k_mlp(const unsigned short* __restrict__ agg,
    const unsigned short* __restrict__ W1, const unsigned short* __restrict__ W2,
    const unsigned short* __restrict__ W3,
    const float* __restrict__ b1, const float* __restrict__ b2, const float* __restrict__ b3,
    const unsigned short* __restrict__ xwb, unsigned short* __restrict__ uout) {
  constexpr int SP = 136;                 // 272 B row stride, 16B-aligned
  __shared__ unsigned short lds[2 * 32 * SP];
  int wave = threadIdx.x >> 6, lane = threadIdx.x & 63;
  int m = lane & 15, q = lane >> 4;
  int row0 = blockIdx.x * 64 + wave * 32;
  unsigned short* L = lds + wave * 32 * SP;
  int ar0 = row0 + m;      if (ar0 >= NN) ar0 = NN - 1;
  int ar1 = row0 + 16 + m; if (ar1 >= NN) ar1 = NN - 1;
  const unsigned short* A0p = agg + (size_t)ar0 * CO;
  const unsigned short* A1p = agg + (size_t)ar1 * CO;

  f32x4 acc[2][8];
#pragma unroll
  for (int g = 0; g < 2; ++g)
#pragma unroll
    for (int t = 0; t < 8; ++t) acc[g][t] = (f32x4){0.f, 0.f, 0.f, 0.f};

  // ---- layer 1 ----
#pragma unroll
  for (int ks = 0; ks < CO; ks += 32) {
    bf16x8 a0 = *(const bf16x8*)(A0p + ks + q * 8);
    bf16x8 a1 = *(const bf16x8*)(A1p + ks + q * 8);
#pragma unroll
    for (int t = 0; t < 8; ++t) {
      bf16x8 b = *(const bf16x8*)(W1 + (size_t)(t * 16 + m) * CO + ks + q * 8);
      acc[0][t] = __builtin_amdgcn_mfma_f32_16x16x32_bf16(a0, b, acc[0][t], 0, 0, 0);
      acc[1][t] = __builtin_amdgcn_mfma_f32_16x16x32_bf16(a1, b, acc[1][t], 0, 0, 0);
    }
  }
#pragma unroll
  for (int t = 0; t < 8; ++t) {
    float bv = b1[t * 16 + m];
#pragma unroll
    for (int g = 0; g < 2; ++g)
#pragma unroll
      for (int r = 0; r < 4; ++r)
        L[(g * 16 + q * 4 + r) * SP + t * 16 + m] = f2bf(fmaxf(acc[g][t][r] + bv, 0.f));
  }
  // ---- layer 2 ----
#pragma unroll
  for (int g = 0; g < 2; ++g)
#pragma unroll
    for (int t = 0; t < 8; ++t) acc[g][t] = (f32x4){0.f, 0.f, 0.f, 0.f};
#pragma unroll
  for (int ks = 0; ks < CO; ks += 32) {
    bf16x8 a0 = *(const bf16x8*)(L + m * SP + ks + q * 8);
    bf16x8 a1 = *(const bf16x8*)(L + (16 + m) * SP + ks + q * 8);
#pragma unroll
    for (int t = 0; t < 8; ++t) {
      bf16x8 b = *(const bf16x8*)(W2 + (size_t)(t * 16 + m) * CO + ks + q * 8);
      acc[0][t] = __builtin_amdgcn_mfma_f32_16x16x32_bf16(a0, b, acc[0][t], 0, 0, 0);
      acc[1][t] = __builtin_amdgcn_mfma_f32_16x16x32_bf16(a1, b, acc[1][t], 0, 0, 0);
    }
  }
#pragma unroll
  for (int t = 0; t < 8; ++t) {
    float bv = b2[t * 16 + m];
#pragma unroll
    for (int g = 0; g < 2; ++g)
#pragma unroll
      for (int r = 0; r < 4; ++r)
        L[(g * 16 + q * 4 + r) * SP + t * 16 + m] = f2bf(fmaxf(acc[g][t][r] + bv, 0.f));
  }
  // ---- layer 3 ----
#pragma unroll
  for (int g = 0; g < 2; ++g)
#pragma unroll
    for (int t = 0; t < 8; ++t) acc[g][t] = (f32x4){0.f, 0.f, 0.f, 0.f};
#pragma unroll
  for (int ks = 0; ks < CO; ks += 32) {
    bf16x8 a0 = *(const bf16x8*)(L + m * SP + ks + q * 8);
    bf16x8 a1 = *(const bf16x8*)(L + (16 + m) * SP + ks + q * 8);
#pragma unroll
    for (int t = 0; t < 8; ++t) {
      bf16x8 b = *(const bf16x8*)(W3 + (size_t)(t * 16 + m) * CO + ks + q * 8);
      acc[0][t] = __builtin_amdgcn_mfma_f32_16x16x32_bf16(a0, b, acc[0][t], 0, 0, 0);
      acc[1][t] = __builtin_amdgcn_mfma_f32_16x16x32_bf16(a1, b, acc[1][t], 0, 0, 0);
    }
  }
  // tanh -> LDS
#pragma unroll
  for (int t = 0; t < 8; ++t) {
    float bv = b3[t * 16 + m];
#pragma unroll
    for (int g = 0; g < 2; ++g)
#pragma unroll
      for (int r = 0; r < 4; ++r) {
        float v = acc[g][t][r] + bv;
        float e = __expf(2.f * v);
        v = 1.f - 2.f / (e + 1.f);        // tanh
        L[(g * 16 + q * 4 + r) * SP + t * 16 + m] = f2bf(v);
      }
  }
  // fused store: u = relu(xw + tanh) with packed b128 traffic
  int ln = lane >> 1, lc = lane & 1;
  int gnode = row0 + ln;
  if (gnode < NN) {
    const unsigned short* xr = xwb + (size_t)gnode * CO;
    unsigned short* ur = uout + (size_t)gnode * CO;
#pragma unroll
    for (int rnd = 0; rnd < 8; ++rnd) {
      int ch = (rnd * 2 + lc) * 8;
      uint4 h = *(const uint4*)(L + ln * SP + ch);
      uint4 xv = *(const uint4*)(xr + ch);
      uint4 o;
      o.x = pk2(fmaxf(bf2f_lo(h.x) + bf2f_lo(xv.x), 0.f), fmaxf(bf2f_hi(h.x) + bf2f_hi(xv.x), 0.f));
      o.y = pk2(fmaxf(bf2f_lo(h.y) + bf2f_lo(xv.y), 0.f), fmaxf(bf2f_hi(h.y) + bf2f_hi(xv.y), 0.f));
      o.z = pk2(fmaxf(bf2f_lo(h.z) + bf2f_lo(xv.z), 0.f), fmaxf(bf2f_hi(h.z) + bf2f_hi(xv.z), 0.f));
      o.w = pk2(fmaxf(bf2f_lo(h.w) + bf2f_lo(xv.w), 0.f), fmaxf(bf2f_hi(h.w) + bf2f_hi(xv.w), 0.f));
      *(uint4*)(ur + ch) = o;
    }
  }
}

// ---------------- final readout ----------------
__global__ __launch_bounds__(256) void k_reduce(const unsigned short* __restrict__ u,
                                                float* __restrict__ g) {
  int ch2 = threadIdx.x & 63;
  int sub = threadIdx.x >> 6;
  float a0 = 0.f, a1 = 0.f;
  for (int n = blockIdx.x * 4 + sub; n < NN; n += gridDim.x * 4) {
    unsigned int p = *(const unsigned int*)(u + (size_t)n * CO + ch2 * 2);
    a0 += bf2f_lo(p); a1 += bf2f_hi(p);
  }
  __shared__ float s0[256], s1[256];
  s0[threadIdx.x] = a0; s1[threadIdx.x] = a1;
  __syncthreads();
  if (sub == 0) {
    a0 = s0[ch2] + s0[64 + ch2] + s0[128 + ch2] + s0[192 + ch2];
    a1 = s1[ch2] + s1[64 + ch2] + s1[128 + ch2] + s1[192 + ch2];
    atomicAdd(&g[ch2 * 2], a0);
    atomicAdd(&g[ch2 * 2 + 1], a1);
  }
}

__global__ void k_final(const float* __restrict__ g, const float* __restrict__ w2,
                        const float* __restrict__ b2, float* __restrict__ outp) {
  __shared__ float sg[128];
  if (threadIdx.x < 128) sg[threadIdx.x] = g[threadIdx.x];
  __syncthreads();
  int j = threadIdx.x;
  if (j < 128) {
    float acc = b2[j];
    for (int c = 0; c < 128; ++c) acc += sg[c] * w2[j * 128 + c];
    outp[j] = acc;
  }
}

extern "C" void kernel_launch(void* const* d_in, const int* in_sizes, int n_in,
                              void* d_out, int out_size, void* d_ws, size_t ws_size,
                              hipStream_t stream) {
  (void)in_sizes; (void)n_in; (void)out_size; (void)ws_size;
  const float* x   = (const float*)d_in[0];
  const float* u0  = (const float*)d_in[1];
  const int*   ei  = (const int*)d_in[2];
  const float* w1W = (const float*)d_in[3];
  const float* w1b = (const float*)d_in[4];
  const float* m1W = (const float*)d_in[5];
  const float* m1b = (const float*)d_in[6];
  const float* m2W = (const float*)d_in[7];
  const float* m2b = (const float*)d_in[8];
  const float* m3W = (const float*)d_in[9];
  const float* m3b = (const float*)d_in[10];
  const float* w2W = (const float*)d_in[11];
  const float* w2b = (const float*)d_in[12];
  const int* esrc = ei;
  const int* edst = ei + NE;

  char* p = (char*)d_ws;
  auto carve = [&](size_t bytes) { char* r = p; p += (bytes + 255) & ~(size_t)255; return r; };
  unsigned short* xwb     = (unsigned short*)carve((size_t)NN * CO * 2);
  unsigned short* ubf     = (unsigned short*)carve((size_t)NN * CO * 2);
  unsigned short* agg     = (unsigned short*)carve((size_t)NN * CO * 2);
  unsigned short* xb      = (unsigned short*)carve((size_t)NN * CI * 2);
  unsigned short* wbf     = (unsigned short*)carve((size_t)57344 * 2);
  int*            row_off = (int*)carve((size_t)(NN + 1) * 4);
  int*            deg     = (int*)carve((size_t)NN * 4);
  int*            cursor  = (int*)carve((size_t)NN * 4);
  int*            ssrc    = (int*)carve((size_t)NE * 4);
  int*            bsum    = (int*)carve((size_t)SCANB * 4);
  int*            boff    = (int*)carve((size_t)SCANB * 4);
  float*          g       = (float*)carve(128 * 4);

  hipMemsetAsync(deg, 0, (size_t)NN * 4, stream);
  hipMemsetAsync(cursor, 0, (size_t)NN * 4, stream);
  hipMemsetAsync(g, 0, 128 * 4, stream);

  k_count<<<(NE + 255) / 256, 256, 0, stream>>>(edst, deg);
  k_scan1<<<SCANB, 256, 0, stream>>>(deg, bsum);
  k_scan2<<<1, 64, 0, stream>>>(bsum, boff);
  k_scan3<<<SCANB, 256, 0, stream>>>(deg, boff, row_off);
  k_fill<<<(NE + 255) / 256, 256, 0, stream>>>(esrc, edst, row_off, cursor, ssrc);
  k_cvt_w<<<(57344 + 255) / 256, 256, 0, stream>>>(w1W, m1W, m2W, m3W, wbf);
  k_cvt4<<<(NN * CI / 4 + 255) / 256, 256, 0, stream>>>(x, xb, NN * CI / 4);
  k_cvt4<<<(NN * CO / 4 + 255) / 256, 256, 0, stream>>>(u0, ubf, NN * CO / 4);

  k_xw<<<(NN + 63) / 64, 256, 0, stream>>>(xb, wbf, w1b, xwb);

  const unsigned short* Wm1 = wbf + 8192;
  const unsigned short* Wm2 = wbf + 8192 + 16384;
  const unsigned short* Wm3 = wbf + 8192 + 2 * 16384;
  const int GM = (NN + 63) / 64;
  for (int it = 0; it < 4; ++it) {
    k_gather<<<(NN + 3) / 4, 256, 0, stream>>>(row_off, ssrc, ubf, agg);
    k_mlp<<<GM, 128, 0, stream>>>(agg, Wm1, Wm2, Wm3, m1b, m2b, m3b, xwb, ubf);
  }

  k_reduce<<<256, 256, 0, stream>>>(ubf, g);
  k_final<<<1, 128, 0, stream>>>(g, w2W, w2b, (float*)d_out);
}